// Round 1
// baseline (2750.696 us; speedup 1.0000x reference)
//
#include <hip/hip_runtime.h>
#include <hip/hip_bf16.h>

#define TPB 256

// ---------------------------------------------------------------------------
// pre = relu((x - b_dec) @ W^T + b_enc), fp64 accumulation (exact ranking).
// 64x64 output tile, K-tile 16, 256 threads -> 4x4 outputs/thread.
// ---------------------------------------------------------------------------
__global__ __launch_bounds__(TPB) void enc_gemm(
    const float* __restrict__ x,     // [B,D]
    const float* __restrict__ W,     // [F,D]
    const float* __restrict__ benc,  // [F]
    const float* __restrict__ bdec,  // [D]
    float* __restrict__ pre,         // [B,F]
    int D, int F) {
  __shared__ float As[64][17];   // +1 pad: breaks 16-way bank conflict on B-frag reads
  __shared__ float Bs[64][17];
  const int bf = blockIdx.x * 64;
  const int bb = blockIdx.y * 64;
  const int tid = threadIdx.x;
  const int tx = tid & 15;
  const int ty = tid >> 4;
  double acc[4][4];
#pragma unroll
  for (int i = 0; i < 4; ++i)
#pragma unroll
    for (int j = 0; j < 4; ++j) acc[i][j] = 0.0;

  for (int k0 = 0; k0 < D; k0 += 16) {
#pragma unroll
    for (int e = 0; e < 4; ++e) {
      int idx = tid + e * TPB;
      int r = idx >> 4, c = idx & 15;
      As[r][c] = x[(size_t)(bb + r) * D + k0 + c] - bdec[k0 + c];
      Bs[r][c] = W[(size_t)(bf + r) * D + k0 + c];
    }
    __syncthreads();
#pragma unroll
    for (int kk = 0; kk < 16; ++kk) {
      double a[4], b[4];
#pragma unroll
      for (int i = 0; i < 4; ++i) a[i] = (double)As[ty * 4 + i][kk];
#pragma unroll
      for (int j = 0; j < 4; ++j) b[j] = (double)Bs[tx * 4 + j][kk];
#pragma unroll
      for (int i = 0; i < 4; ++i)
#pragma unroll
        for (int j = 0; j < 4; ++j) acc[i][j] += a[i] * b[j];
    }
    __syncthreads();
  }
#pragma unroll
  for (int i = 0; i < 4; ++i) {
    int bidx = bb + ty * 4 + i;
#pragma unroll
    for (int j = 0; j < 4; ++j) {
      int fidx = bf + tx * 4 + j;
      float r = (float)(acc[i][j] + (double)benc[fidx]);
      pre[(size_t)bidx * F + fidx] = r > 0.0f ? r : 0.0f;
    }
  }
}

// ---------------------------------------------------------------------------
// Per-row top-64 via MSB-first radix select on float bits (all vals >= 0
// after relu, so uint order == float order). Tie-break: lowest index,
// matching jax.lax.top_k inclusion semantics. Output order is arbitrary
// (all consumers are order-independent sums/sets).
// ---------------------------------------------------------------------------
__global__ __launch_bounds__(TPB) void topk64(
    const float* __restrict__ pre, int F,
    float* __restrict__ vals, int* __restrict__ idxs) {
  const int b = blockIdx.x;
  const float* row = pre + (size_t)b * F;
  __shared__ unsigned hist[256];
  __shared__ unsigned sh_prefix, sh_need;
  __shared__ int sh_gt, sh_neq;
  __shared__ int eqidx[256];
  const int tid = threadIdx.x;
  if (tid == 0) { sh_prefix = 0u; sh_need = 64u; }
  __syncthreads();

  for (int pass = 0; pass < 4; ++pass) {
    const int shift = 24 - 8 * pass;
    hist[tid] = 0u;
    __syncthreads();
    const unsigned prefix = sh_prefix;
    const unsigned maskhi = (pass == 0) ? 0u : (0xFFFFFFFFu << (shift + 8));
    for (int i = tid; i < F; i += TPB) {
      unsigned k = __float_as_uint(row[i]);
      if ((k & maskhi) == prefix) atomicAdd(&hist[(k >> shift) & 255], 1u);
    }
    __syncthreads();
    if (tid == 0) {
      unsigned need = sh_need, cum = 0;
      int bsel = 0;
      for (int bin = 255; bin >= 0; --bin) {
        if (cum + hist[bin] >= need) { bsel = bin; break; }
        cum += hist[bin];
      }
      sh_prefix = prefix | ((unsigned)bsel << shift);
      sh_need = need - cum;   // rank within the selected bin
    }
    __syncthreads();
  }

  const unsigned T = sh_prefix;
  const unsigned need = sh_need;  // # of ==T elements to include
  if (tid == 0) { sh_gt = 0; sh_neq = 0; }
  __syncthreads();
  const float tval = __uint_as_float(T);
  float* ovals = vals + (size_t)b * 64;
  int* oidx = idxs + (size_t)b * 64;
  for (int i = tid; i < F; i += TPB) {
    float v = row[i];
    unsigned k = __float_as_uint(v);
    if (k > T) {
      int p = atomicAdd(&sh_gt, 1);
      ovals[p] = v; oidx[p] = i;
    } else if (k == T) {
      int e = atomicAdd(&sh_neq, 1);
      if (e < 256) eqidx[e] = i;
    }
  }
  __syncthreads();
  if (tid == 0) {
    int g = sh_gt;                       // == 64 - need by radix invariant
    int ne = sh_neq < 256 ? sh_neq : 256;
    for (int r = 0; r < (int)need; ++r) {  // `need` smallest indices among ==T
      int mpos = r;
      for (int q = r + 1; q < ne; ++q)
        if (eqidx[q] < eqidx[mpos]) mpos = q;
      int t = eqidx[r]; eqidx[r] = eqidx[mpos]; eqidx[mpos] = t;
      ovals[g + r] = tval; oidx[g + r] = eqidx[r];
    }
  }
}

// ---------------------------------------------------------------------------
// Transpose W_dec (D,F) -> (F,D) so decode/contrib read contiguous columns.
// ---------------------------------------------------------------------------
__global__ __launch_bounds__(TPB) void transpose_df(
    const float* __restrict__ in,  // [D,F]
    float* __restrict__ out,       // [F,D]
    int D, int F) {
  __shared__ float tile[32][33];
  const int f0 = blockIdx.x * 32;
  const int d0 = blockIdx.y * 32;
  const int tx = threadIdx.x & 31;
  const int ty = threadIdx.x >> 5;  // 0..7
#pragma unroll
  for (int i = 0; i < 4; ++i)
    tile[ty + i * 8][tx] = in[(size_t)(d0 + ty + i * 8) * F + f0 + tx];
  __syncthreads();
#pragma unroll
  for (int i = 0; i < 4; ++i)
    out[(size_t)(f0 + ty + i * 8) * D + d0 + tx] = tile[tx][ty + i * 8];
}

// ---------------------------------------------------------------------------
// Sparse decode: out[b,:] = bdec + sum_k vals[b,k] * WT[idx[b,k], :]
// ---------------------------------------------------------------------------
__global__ __launch_bounds__(TPB) void decode64(
    const float* __restrict__ WT,    // [F,D]
    const float* __restrict__ bdec,  // [D]
    const float* __restrict__ vals, const int* __restrict__ idxs,
    float* __restrict__ out, int D) {
  const int b = blockIdx.x;
  __shared__ float sv[64];
  __shared__ int si[64];
  const int tid = threadIdx.x;
  if (tid < 64) {
    sv[tid] = vals[(size_t)b * 64 + tid];
    si[tid] = idxs[(size_t)b * 64 + tid];
  }
  __syncthreads();
  for (int d = tid; d < D; d += TPB) {
    float acc = bdec[d];
#pragma unroll 8
    for (int k = 0; k < 64; ++k)
      acc += sv[k] * WT[(size_t)si[k] * D + d];
    out[(size_t)b * D + d] = acc;
  }
}

// ---------------------------------------------------------------------------
// approx_acts[b,kd] = sum over (c matches): up_val[ku] *
//                     dot(W_enc_down[down_idx[kd]], W_dec_up[:, up_idx[ku]])
// Phase B finds matches (few), phase C does block-cooperative dots.
// ---------------------------------------------------------------------------
__global__ __launch_bounds__(TPB) void contrib(
    const int* __restrict__ conn,     // [F,C]
    const float* __restrict__ Wencd,  // [F,D]
    const float* __restrict__ WTdecu, // [F,D]  (transposed W_dec_up)
    const float* __restrict__ up_vals, const int* __restrict__ up_idx,
    const int* __restrict__ down_idx,
    float* __restrict__ approx, int D, int C) {
  const int b = blockIdx.x;
  __shared__ int sui[64];
  __shared__ float suv[64];
  __shared__ int sdi[64];
  __shared__ float sacc[64];
  __shared__ int queue[2048];
  __shared__ int qn;
  __shared__ float red[TPB];
  const int tid = threadIdx.x;
  if (tid < 64) {
    sui[tid] = up_idx[(size_t)b * 64 + tid];
    suv[tid] = up_vals[(size_t)b * 64 + tid];
    sdi[tid] = down_idx[(size_t)b * 64 + tid];
    sacc[tid] = 0.0f;
  }
  if (tid == 0) qn = 0;
  __syncthreads();
  const int npairs = 64 * C;
  for (int p = tid; p < npairs; p += TPB) {
    int kd = p / C, c = p - kd * C;
    int f = conn[(size_t)sdi[kd] * C + c];
    if (f < 0) continue;
    for (int ku = 0; ku < 64; ++ku) {
      if (sui[ku] == f) {                  // up_idx distinct -> at most one
        int q = atomicAdd(&qn, 1);
        queue[q] = (kd << 8) | ku;
        break;
      }
    }
  }
  __syncthreads();
  const int n = qn;
  for (int q = 0; q < n; ++q) {
    int kd = queue[q] >> 8, ku = queue[q] & 255;
    const float* wd = Wencd + (size_t)sdi[kd] * D;
    const float* wu = WTdecu + (size_t)sui[ku] * D;
    float s = 0.0f;
    for (int d = tid; d < D; d += TPB) s += wd[d] * wu[d];
    red[tid] = s;
    __syncthreads();
    for (int off = TPB / 2; off > 0; off >>= 1) {
      if (tid < off) red[tid] += red[tid + off];
      __syncthreads();
    }
    if (tid == 0) sacc[kd] += suv[ku] * red[0];
    __syncthreads();
  }
  if (tid < 64) approx[(size_t)b * 64 + tid] = sacc[tid];
}

// ---------------------------------------------------------------------------
extern "C" void kernel_launch(void* const* d_in, const int* in_sizes, int n_in,
                              void* d_out, int out_size, void* d_ws, size_t ws_size,
                              hipStream_t stream) {
  const float* x_up   = (const float*)d_in[0];
  const float* x_down = (const float*)d_in[1];
  const float* Wenc_u = (const float*)d_in[2];
  const float* benc_u = (const float*)d_in[3];
  const float* Wdec_u = (const float*)d_in[4];
  const float* bdec_u = (const float*)d_in[5];
  const float* Wenc_d = (const float*)d_in[6];
  const float* benc_d = (const float*)d_in[7];
  const float* Wdec_d = (const float*)d_in[8];
  const float* bdec_d = (const float*)d_in[9];
  const int*   conn   = (const int*)d_in[10];

  const int D = in_sizes[5];           // 768
  const int B = in_sizes[0] / D;       // 1024
  const int F = in_sizes[3];           // 24576
  const int C = in_sizes[10] / F;      // 32

  float* out = (float*)d_out;
  float* wsf = (float*)d_ws;

  // ws layout: [pre (B*F fp32, later recycled for W_dec^T (F*D <= B*F))]
  //            [up_vals][up_idx][dn_vals][dn_idx][approx]  (B*64 each)
  const size_t preN = (size_t)B * F;
  float* pre     = wsf;
  float* up_vals = wsf + preN;
  int*   up_idx  = (int*)(up_vals + (size_t)B * 64);
  float* dn_vals = (float*)(up_idx + (size_t)B * 64);
  int*   dn_idx  = (int*)(dn_vals + (size_t)B * 64);
  float* approx  = (float*)(dn_idx + (size_t)B * 64);

  dim3 gemm_grid(F / 64, B / 64);
  dim3 tr_grid(F / 32, D / 32);

  // upstream encode + topk
  enc_gemm<<<gemm_grid, TPB, 0, stream>>>(x_up, Wenc_u, benc_u, bdec_u, pre, D, F);
  topk64<<<B, TPB, 0, stream>>>(pre, F, up_vals, up_idx);
  // downstream encode + topk (reuses pre buffer)
  enc_gemm<<<gemm_grid, TPB, 0, stream>>>(x_down, Wenc_d, benc_d, bdec_d, pre, D, F);
  topk64<<<B, TPB, 0, stream>>>(pre, F, dn_vals, dn_idx);

  // pre buffer now free -> W_dec_up^T
  float* WT = pre;
  transpose_df<<<tr_grid, TPB, 0, stream>>>(Wdec_u, WT, D, F);
  decode64<<<B, TPB, 0, stream>>>(WT, bdec_u, up_vals, up_idx, out, D);
  contrib<<<B, TPB, 0, stream>>>(conn, Wenc_d, WT, up_vals, up_idx, dn_idx,
                                 approx, D, C);
  // W_dec_down^T (overwrites WT after contrib consumed it)
  transpose_df<<<tr_grid, TPB, 0, stream>>>(Wdec_d, WT, D, F);
  decode64<<<B, TPB, 0, stream>>>(WT, bdec_d, approx, dn_idx, out + (size_t)B * D, D);
}

// Round 2
// 961.349 us; speedup vs baseline: 2.8613x; 2.8613x over previous
//
#include <hip/hip_runtime.h>
#include <hip/hip_bf16.h>

#define TPB 256

typedef __attribute__((ext_vector_type(4))) float f32x4;
typedef __bf16 bf16x8 __attribute__((ext_vector_type(8)));

// ---------------------------------------------------------------------------
// pre = relu((x - b_dec) @ W^T + b_enc), bf16-split MFMA (3-product scheme).
// 128x128 tile, BK=32, 4 waves (2x2 of 64x64), mfma_f32_16x16x32_bf16.
// Approx error vs exact fp64: |err| <~ 3e-4 (handled by topk_sel's fp64
// boundary refinement with eps = 3e-3).
// LDS layout: fragment-permuted [g][row] of 16B entries -> conflict-free
// ds_read_b128 / ds_write_b128 (consecutive lanes -> consecutive 16B).
// ---------------------------------------------------------------------------
__global__ __launch_bounds__(TPB) void enc_gemm(
    const float* __restrict__ x,     // [B,D]
    const float* __restrict__ W,     // [F,D]
    const float* __restrict__ benc,  // [F]
    const float* __restrict__ bdec,  // [D]
    float* __restrict__ pre,         // [B,F]
    int D, int F) {
  __shared__ bf16x8 Ah[512], Al[512], Wh[512], Wl[512];  // 4 x 8 KB
  const int bf0 = blockIdx.x * 128;
  const int bb  = blockIdx.y * 128;
  const int t = threadIdx.x;
  const int r  = t & 127;     // staging row within tile
  const int gb = t >> 7;      // staging K-group base (0/1), +2 for 2nd frag

  const int lane = t & 63;
  const int wv   = t >> 6;
  const int wm   = (wv >> 1) * 64;
  const int wn   = (wv & 1) * 64;
  const int lrow = lane & 15;
  const int quad = lane >> 4;

  f32x4 acc[4][4];
#pragma unroll
  for (int i = 0; i < 4; ++i)
#pragma unroll
    for (int j = 0; j < 4; ++j) acc[i][j] = (f32x4){0.f, 0.f, 0.f, 0.f};

  for (int k0 = 0; k0 < D; k0 += 32) {
    // ---- stage: global fp32 -> split hi/lo bf16 -> permuted LDS ----
    f32x4 a0[2], a1[2], w0[2], w1[2], d0[2], d1[2];
#pragma unroll
    for (int e = 0; e < 2; ++e) {
      const int g = gb + e * 2;
      const f32x4* ap = (const f32x4*)(x + (size_t)(bb + r) * D + k0 + g * 8);
      const f32x4* dp = (const f32x4*)(bdec + k0 + g * 8);
      const f32x4* wp = (const f32x4*)(W + (size_t)(bf0 + r) * D + k0 + g * 8);
      a0[e] = ap[0]; a1[e] = ap[1];
      d0[e] = dp[0]; d1[e] = dp[1];
      w0[e] = wp[0]; w1[e] = wp[1];
    }
    __syncthreads();  // previous iteration's readers done
#pragma unroll
    for (int e = 0; e < 2; ++e) {
      const int g = gb + e * 2;
      const int q = g * 128 + r;
      bf16x8 hi, lo;
#pragma unroll
      for (int u = 0; u < 8; ++u) {
        float v = (u < 4) ? (a0[e][u] - d0[e][u]) : (a1[e][u - 4] - d1[e][u - 4]);
        __bf16 h = (__bf16)v;
        hi[u] = h;
        lo[u] = (__bf16)(v - (float)h);
      }
      Ah[q] = hi; Al[q] = lo;
#pragma unroll
      for (int u = 0; u < 8; ++u) {
        float v = (u < 4) ? w0[e][u] : w1[e][u - 4];
        __bf16 h = (__bf16)v;
        hi[u] = h;
        lo[u] = (__bf16)(v - (float)h);
      }
      Wh[q] = hi; Wl[q] = lo;
    }
    __syncthreads();
    // ---- MFMA ----
    bf16x8 ah[4], al[4];
#pragma unroll
    for (int i = 0; i < 4; ++i) {
      ah[i] = Ah[quad * 128 + wm + i * 16 + lrow];
      al[i] = Al[quad * 128 + wm + i * 16 + lrow];
    }
#pragma unroll
    for (int j = 0; j < 4; ++j) {
      bf16x8 bh = Wh[quad * 128 + wn + j * 16 + lrow];
      bf16x8 bl = Wl[quad * 128 + wn + j * 16 + lrow];
#pragma unroll
      for (int i = 0; i < 4; ++i) {
        acc[i][j] = __builtin_amdgcn_mfma_f32_16x16x32_bf16(ah[i], bh, acc[i][j], 0, 0, 0);
        acc[i][j] = __builtin_amdgcn_mfma_f32_16x16x32_bf16(ah[i], bl, acc[i][j], 0, 0, 0);
        acc[i][j] = __builtin_amdgcn_mfma_f32_16x16x32_bf16(al[i], bh, acc[i][j], 0, 0, 0);
      }
    }
  }
  // ---- epilogue: +benc, relu, store (C/D: col=lane&15, row=quad*4+reg) ----
#pragma unroll
  for (int j = 0; j < 4; ++j) {
    const int col = bf0 + wn + j * 16 + lrow;
    const float bc = benc[col];
#pragma unroll
    for (int i = 0; i < 4; ++i) {
      const int row0 = bb + wm + i * 16 + quad * 4;
#pragma unroll
      for (int rg = 0; rg < 4; ++rg) {
        float v = acc[i][j][rg] + bc;
        pre[(size_t)(row0 + rg) * F + col] = v > 0.f ? v : 0.f;
      }
    }
  }
}

// ---------------------------------------------------------------------------
// Select top-64 per row from approx pre, with fp64 refinement at the
// boundary so the selected SET matches exact-fp64 ranking (ties -> lowest
// index, matching jax.lax.top_k).
//  1. collect vals > thr into LDS (adaptive thr, 1 pass typical)
//  2. in-LDS radix-select the 64th approx value T
//  3. classify from global: v > T+eps -> sure-in (emit approx);
//     |v-T| <= eps -> band: recompute exact fp64, rank, take remainder
// ---------------------------------------------------------------------------
#define TK_CAP 2048
#define BAND_CAP 128
#define TK_EPS 3e-3f

__global__ __launch_bounds__(TPB) void topk_sel(
    const float* __restrict__ pre,   // [B,F] approx
    const float* __restrict__ x,     // [B,D]
    const float* __restrict__ W,     // [F,D]
    const float* __restrict__ benc,  // [F]
    const float* __restrict__ bdec,  // [D]
    float* __restrict__ vals, int* __restrict__ idxs,
    int D, int F) {
  const int b = blockIdx.x;
  const int tid = threadIdx.x;
  const float* row = pre + (size_t)b * F;

  __shared__ float cval[TK_CAP];
  __shared__ unsigned hist[256];
  __shared__ double xs[768];
  __shared__ int bcand[BAND_CAP];
  __shared__ double bexact[BAND_CAP];
  __shared__ int sh_cnt, sh_out, sh_band;
  __shared__ float sh_thr;
  __shared__ unsigned sh_prefix, sh_need;

  // cache x - bdec as double for exact recompute
  for (int d = tid; d < D; d += TPB)
    xs[d] = (double)x[(size_t)b * D + d] - (double)bdec[d];

  if (tid == 0) sh_thr = 1.75f;
  // ---- 1. adaptive collection ----
  int n;
  for (;;) {
    __syncthreads();
    if (tid == 0) sh_cnt = 0;
    __syncthreads();
    const float thr = sh_thr;
    for (int i = tid * 4; i < F; i += TPB * 4) {
      f32x4 v = *(const f32x4*)(row + i);
#pragma unroll
      for (int u = 0; u < 4; ++u) {
        if (v[u] > thr) {
          int p = atomicAdd(&sh_cnt, 1);
          if (p < TK_CAP) cval[p] = v[u];
        }
      }
    }
    __syncthreads();
    n = sh_cnt;
    if (n >= 64 && n <= TK_CAP) break;
    if (tid == 0) sh_thr = (n < 64) ? thr * 0.5f : thr * 1.25f;
  }

  // ---- 2. radix select 64th largest among collected (all > 0) ----
  if (tid == 0) { sh_prefix = 0u; sh_need = 64u; }
  __syncthreads();
  for (int pass = 0; pass < 4; ++pass) {
    const int shift = 24 - 8 * pass;
    hist[tid] = 0u;
    __syncthreads();
    const unsigned prefix = sh_prefix;
    const unsigned maskhi = (pass == 0) ? 0u : (0xFFFFFFFFu << (shift + 8));
    for (int q = tid; q < n; q += TPB) {
      unsigned k = __float_as_uint(cval[q]);
      if ((k & maskhi) == prefix) atomicAdd(&hist[(k >> shift) & 255], 1u);
    }
    __syncthreads();
    if (tid == 0) {
      unsigned need = sh_need, cum = 0;
      int bsel = 0;
      for (int bin = 255; bin >= 0; --bin) {
        if (cum + hist[bin] >= need) { bsel = bin; break; }
        cum += hist[bin];
      }
      sh_prefix = prefix | ((unsigned)bsel << shift);
      sh_need = need - cum;
    }
    __syncthreads();
  }
  const float Tf = __uint_as_float(sh_prefix);
  const float hicut = Tf + TK_EPS, locut = Tf - TK_EPS;

  // ---- 3. classify from global ----
  if (tid == 0) { sh_out = 0; sh_band = 0; }
  __syncthreads();
  float* ovals = vals + (size_t)b * 64;
  int* oidx = idxs + (size_t)b * 64;
  for (int i = tid * 4; i < F; i += TPB * 4) {
    f32x4 v = *(const f32x4*)(row + i);
#pragma unroll
    for (int u = 0; u < 4; ++u) {
      if (v[u] > hicut) {            // provably in top-64
        int p = atomicAdd(&sh_out, 1);
        ovals[p] = v[u]; oidx[p] = i + u;
      } else if (v[u] >= locut) {    // boundary band -> exact rerank
        int q = atomicAdd(&sh_band, 1);
        if (q < BAND_CAP) bcand[q] = i + u;
      }
    }
  }
  __syncthreads();
  const int s = sh_out;
  const int bn = sh_band < BAND_CAP ? sh_band : BAND_CAP;
  const int needk = 64 - s;
  // exact fp64 recompute of band candidates (wave-cooperative dots)
  const int lane = tid & 63, wv = tid >> 6;
  for (int q = wv; q < bn; q += 4) {
    const float* wr = W + (size_t)bcand[q] * D;
    double sum = 0.0;
    for (int d = lane; d < D; d += 64) sum += xs[d] * (double)wr[d];
#pragma unroll
    for (int m = 32; m > 0; m >>= 1) sum += __shfl_xor(sum, m, 64);
    if (lane == 0) {
      double v = sum + (double)benc[bcand[q]];
      bexact[q] = v > 0.0 ? v : 0.0;
    }
  }
  __syncthreads();
  if (tid < bn) {
    const double v = bexact[tid];
    const int id = bcand[tid];
    int rank = 0;
    for (int j = 0; j < bn; ++j)
      rank += (bexact[j] > v) || (bexact[j] == v && bcand[j] < id);
    if (rank < needk) { ovals[s + rank] = (float)v; oidx[s + rank] = id; }
  }
}

// ---------------------------------------------------------------------------
// Transpose W_dec (D,F) -> (F,D)
// ---------------------------------------------------------------------------
__global__ __launch_bounds__(TPB) void transpose_df(
    const float* __restrict__ in, float* __restrict__ out, int D, int F) {
  __shared__ float tile[32][33];
  const int f0 = blockIdx.x * 32;
  const int d0 = blockIdx.y * 32;
  const int tx = threadIdx.x & 31;
  const int ty = threadIdx.x >> 5;
#pragma unroll
  for (int i = 0; i < 4; ++i)
    tile[ty + i * 8][tx] = in[(size_t)(d0 + ty + i * 8) * F + f0 + tx];
  __syncthreads();
#pragma unroll
  for (int i = 0; i < 4; ++i)
    out[(size_t)(f0 + ty + i * 8) * D + d0 + tx] = tile[tx][ty + i * 8];
}

// ---------------------------------------------------------------------------
// Sparse decode: out[b,:] = bdec + sum_k vals[b,k] * WT[idx[b,k], :]
// ---------------------------------------------------------------------------
__global__ __launch_bounds__(TPB) void decode64(
    const float* __restrict__ WT, const float* __restrict__ bdec,
    const float* __restrict__ vals, const int* __restrict__ idxs,
    float* __restrict__ out, int D) {
  const int b = blockIdx.x;
  __shared__ float sv[64];
  __shared__ int si[64];
  const int tid = threadIdx.x;
  if (tid < 64) {
    sv[tid] = vals[(size_t)b * 64 + tid];
    si[tid] = idxs[(size_t)b * 64 + tid];
  }
  __syncthreads();
  for (int d = tid; d < D; d += TPB) {
    float acc = bdec[d];
#pragma unroll 8
    for (int k = 0; k < 64; ++k)
      acc += sv[k] * WT[(size_t)si[k] * D + d];
    out[(size_t)b * D + d] = acc;
  }
}

// ---------------------------------------------------------------------------
// approx_acts[b,kd] via connection matching + block-cooperative dots
// ---------------------------------------------------------------------------
__global__ __launch_bounds__(TPB) void contrib(
    const int* __restrict__ conn, const float* __restrict__ Wencd,
    const float* __restrict__ WTdecu,
    const float* __restrict__ up_vals, const int* __restrict__ up_idx,
    const int* __restrict__ down_idx,
    float* __restrict__ approx, int D, int C) {
  const int b = blockIdx.x;
  __shared__ int sui[64];
  __shared__ float suv[64];
  __shared__ int sdi[64];
  __shared__ float sacc[64];
  __shared__ int queue[2048];
  __shared__ int qn;
  __shared__ float red[TPB];
  const int tid = threadIdx.x;
  if (tid < 64) {
    sui[tid] = up_idx[(size_t)b * 64 + tid];
    suv[tid] = up_vals[(size_t)b * 64 + tid];
    sdi[tid] = down_idx[(size_t)b * 64 + tid];
    sacc[tid] = 0.0f;
  }
  if (tid == 0) qn = 0;
  __syncthreads();
  const int npairs = 64 * C;
  for (int p = tid; p < npairs; p += TPB) {
    int kd = p / C, c = p - kd * C;
    int f = conn[(size_t)sdi[kd] * C + c];
    if (f < 0) continue;
    for (int ku = 0; ku < 64; ++ku) {
      if (sui[ku] == f) {
        int q = atomicAdd(&qn, 1);
        queue[q] = (kd << 8) | ku;
        break;
      }
    }
  }
  __syncthreads();
  const int n = qn;
  for (int q = 0; q < n; ++q) {
    int kd = queue[q] >> 8, ku = queue[q] & 255;
    const float* wd = Wencd + (size_t)sdi[kd] * D;
    const float* wu = WTdecu + (size_t)sui[ku] * D;
    float s = 0.0f;
    for (int d = tid; d < D; d += TPB) s += wd[d] * wu[d];
    red[tid] = s;
    __syncthreads();
    for (int off = TPB / 2; off > 0; off >>= 1) {
      if (tid < off) red[tid] += red[tid + off];
      __syncthreads();
    }
    if (tid == 0) sacc[kd] += suv[ku] * red[0];
    __syncthreads();
  }
  if (tid < 64) approx[(size_t)b * 64 + tid] = sacc[tid];
}

// ---------------------------------------------------------------------------
extern "C" void kernel_launch(void* const* d_in, const int* in_sizes, int n_in,
                              void* d_out, int out_size, void* d_ws, size_t ws_size,
                              hipStream_t stream) {
  const float* x_up   = (const float*)d_in[0];
  const float* x_down = (const float*)d_in[1];
  const float* Wenc_u = (const float*)d_in[2];
  const float* benc_u = (const float*)d_in[3];
  const float* Wdec_u = (const float*)d_in[4];
  const float* bdec_u = (const float*)d_in[5];
  const float* Wenc_d = (const float*)d_in[6];
  const float* benc_d = (const float*)d_in[7];
  const float* Wdec_d = (const float*)d_in[8];
  const float* bdec_d = (const float*)d_in[9];
  const int*   conn   = (const int*)d_in[10];

  const int D = in_sizes[5];
  const int B = in_sizes[0] / D;
  const int F = in_sizes[3];
  const int C = in_sizes[10] / F;

  float* out = (float*)d_out;
  float* wsf = (float*)d_ws;

  const size_t preN = (size_t)B * F;
  float* pre     = wsf;
  float* up_vals = wsf + preN;
  int*   up_idx  = (int*)(up_vals + (size_t)B * 64);
  float* dn_vals = (float*)(up_idx + (size_t)B * 64);
  int*   dn_idx  = (int*)(dn_vals + (size_t)B * 64);
  float* approx  = (float*)(dn_idx + (size_t)B * 64);

  dim3 gemm_grid(F / 128, B / 128);
  dim3 tr_grid(F / 32, D / 32);

  enc_gemm<<<gemm_grid, TPB, 0, stream>>>(x_up, Wenc_u, benc_u, bdec_u, pre, D, F);
  topk_sel<<<B, TPB, 0, stream>>>(pre, x_up, Wenc_u, benc_u, bdec_u,
                                  up_vals, up_idx, D, F);
  enc_gemm<<<gemm_grid, TPB, 0, stream>>>(x_down, Wenc_d, benc_d, bdec_d, pre, D, F);
  topk_sel<<<B, TPB, 0, stream>>>(pre, x_down, Wenc_d, benc_d, bdec_d,
                                  dn_vals, dn_idx, D, F);

  float* WT = pre;  // pre free after 2nd topk
  transpose_df<<<tr_grid, TPB, 0, stream>>>(Wdec_u, WT, D, F);
  decode64<<<B, TPB, 0, stream>>>(WT, bdec_u, up_vals, up_idx, out, D);
  contrib<<<B, TPB, 0, stream>>>(conn, Wenc_d, WT, up_vals, up_idx, dn_idx,
                                 approx, D, C);
  transpose_df<<<tr_grid, TPB, 0, stream>>>(Wdec_d, WT, D, F);
  decode64<<<B, TPB, 0, stream>>>(WT, bdec_d, approx, dn_idx, out + (size_t)B * D, D);
}

// Round 3
// 844.587 us; speedup vs baseline: 3.2569x; 1.1382x over previous
//
#include <hip/hip_runtime.h>
#include <hip/hip_bf16.h>

#define TPB 256

typedef __attribute__((ext_vector_type(4))) float f32x4;
typedef __bf16 bf16x8 __attribute__((ext_vector_type(8)));

// async global->LDS, 16B per lane. LDS dest must be wave-uniform base;
// HW writes lane i's 16B at base + i*16 (m97-verified pattern).
__device__ __forceinline__ void gload16(const bf16x8* g, bf16x8* l) {
  __builtin_amdgcn_global_load_lds(
      (const __attribute__((address_space(1))) unsigned int*)g,
      (__attribute__((address_space(3))) unsigned int*)l, 16, 0, 0);
}

// ---------------------------------------------------------------------------
// pack_tiles: fp32 [R,D] (optionally minus `sub`) -> bf16 tile-permuted
// layout [R/128][D/32][512] of bf16x8, where entry q = g*128 + row holds
// src[r0+row][k0+g*8 .. +8]. This is exactly the LDS image enc_gemm_bf wants,
// so the GEMM can global_load_lds it with lane-linear addressing.
// ---------------------------------------------------------------------------
__global__ __launch_bounds__(TPB) void pack_tiles(
    const float* __restrict__ src, const float* __restrict__ sub,
    bf16x8* __restrict__ dst, int D) {
  const int r0 = blockIdx.x * 128;
  const int k0 = blockIdx.y * 32;
  const size_t tile = ((size_t)blockIdx.x * gridDim.y + blockIdx.y) * 512;
#pragma unroll
  for (int e = 0; e < 2; ++e) {
    const int q = e * 256 + threadIdx.x;
    const int row = q & 127, g = q >> 7;
    const float* s = src + (size_t)(r0 + row) * D + k0 + g * 8;
    f32x4 v0 = *(const f32x4*)s;
    f32x4 v1 = *(const f32x4*)(s + 4);
    if (sub) {
      const float* bp = sub + k0 + g * 8;
      v0 = v0 - *(const f32x4*)bp;
      v1 = v1 - *(const f32x4*)(bp + 4);
    }
    bf16x8 o;
#pragma unroll
    for (int u = 0; u < 4; ++u) o[u] = (__bf16)v0[u];
#pragma unroll
    for (int u = 0; u < 4; ++u) o[u + 4] = (__bf16)v1[u];
    dst[tile + q] = o;
  }
}

// ---------------------------------------------------------------------------
// pre = relu(A @ W^T + benc) in pure bf16 MFMA (1 product), pre stored bf16.
// m97 structure: global_load_lds staging + ds_read_b128 frags + 16 MFMA/wave.
// 128x128 tile, BK=32, 4 waves (2x2 of 64x64).
// ---------------------------------------------------------------------------
__global__ __launch_bounds__(TPB) void enc_gemm_bf(
    const bf16x8* __restrict__ A,   // packed [B/128][nkt][512]
    const bf16x8* __restrict__ W,   // packed [F/128][nkt][512]
    const float* __restrict__ benc,
    __bf16* __restrict__ pre,       // [B,F] bf16
    int nkt, int F) {
  __shared__ bf16x8 As[512], Ws[512];  // 8 KB each
  const int t = threadIdx.x;
  const int lane = t & 63, wv = t >> 6;
  const int wm = (wv >> 1) * 64, wn = (wv & 1) * 64;
  const int lrow = lane & 15, quad = lane >> 4;
  const size_t Ab = (size_t)blockIdx.y * nkt * 512;
  const size_t Wb = (size_t)blockIdx.x * nkt * 512;

  f32x4 acc[4][4];
#pragma unroll
  for (int i = 0; i < 4; ++i)
#pragma unroll
    for (int j = 0; j < 4; ++j) acc[i][j] = (f32x4){0.f, 0.f, 0.f, 0.f};

  for (int kt = 0; kt < nkt; ++kt) {
    __syncthreads();  // prev tile's readers done
    const bf16x8* ag = A + Ab + (size_t)kt * 512 + wv * 128;
    const bf16x8* wg = W + Wb + (size_t)kt * 512 + wv * 128;
    bf16x8* al = As + wv * 128;  // wave-uniform LDS base
    bf16x8* wl = Ws + wv * 128;
    gload16(ag + lane, al);
    gload16(ag + 64 + lane, al + 64);
    gload16(wg + lane, wl);
    gload16(wg + 64 + lane, wl + 64);
    __syncthreads();  // compiler drains vmcnt before barrier
    bf16x8 af[4];
#pragma unroll
    for (int i = 0; i < 4; ++i) af[i] = As[quad * 128 + wm + i * 16 + lrow];
#pragma unroll
    for (int j = 0; j < 4; ++j) {
      bf16x8 bfr = Ws[quad * 128 + wn + j * 16 + lrow];
#pragma unroll
      for (int i = 0; i < 4; ++i)
        acc[i][j] = __builtin_amdgcn_mfma_f32_16x16x32_bf16(af[i], bfr, acc[i][j], 0, 0, 0);
    }
  }
  // epilogue: C/D layout col=lane&15, row=quad*4+reg (m89-verified)
  const int bf0 = blockIdx.x * 128, bb = blockIdx.y * 128;
#pragma unroll
  for (int j = 0; j < 4; ++j) {
    const int col = bf0 + wn + j * 16 + lrow;
    const float bc = benc[col];
#pragma unroll
    for (int i = 0; i < 4; ++i) {
      const int row0 = bb + wm + i * 16 + quad * 4;
#pragma unroll
      for (int rg = 0; rg < 4; ++rg) {
        float v = acc[i][j][rg] + bc;
        v = v > 0.f ? v : 0.f;
        pre[(size_t)(row0 + rg) * F + col] = (__bf16)v;
      }
    }
  }
}

// ---------------------------------------------------------------------------
// topk_sel: single-pass select of exact-fp64 top-64 from approx bf16 pre.
//  1. collect (val,idx) with val > thr into LDS (adaptive, 1 global pass)
//  2. in-LDS radix-select T = 64th-largest approx
//  3. classify the collected list: > T+eps sure-in; [T-eps,T+eps] band
//  4. band: exact fp64 dot, rank (ties -> lowest idx), fill remaining slots
//  5. if need_exact: recompute all 64 selected vals exactly in fp64
// Correct iff |approx-exact| <= eps/2 (bound ~0.024 incl bf16 quant; eps/2
// = 0.0375) and thr < T - eps (checked, with retry).
// ---------------------------------------------------------------------------
#define TK_CAP 2048
#define BAND_CAP 256
#define TK_EPS 0.075f

__global__ __launch_bounds__(TPB) void topk_sel(
    const unsigned short* __restrict__ pre,  // [B,F] bf16 bits
    const float* __restrict__ x, const float* __restrict__ W,
    const float* __restrict__ benc, const float* __restrict__ bdec,
    float* __restrict__ vals, int* __restrict__ idxs,
    int D, int F, int need_exact) {
  const int b = blockIdx.x;
  const int tid = threadIdx.x;
  const unsigned short* row = pre + (size_t)b * F;

  __shared__ float cval[TK_CAP];
  __shared__ int cidx[TK_CAP];
  __shared__ unsigned hist[256];
  __shared__ double xs[768];
  __shared__ int bcand[BAND_CAP];
  __shared__ double bexact[BAND_CAP];
  __shared__ int sh_cnt, sh_out, sh_band;
  __shared__ float sh_thr;
  __shared__ unsigned sh_prefix, sh_need;

  for (int d = tid; d < D; d += TPB)
    xs[d] = (double)x[(size_t)b * D + d] - (double)bdec[d];
  if (tid == 0) sh_thr = 1.75f;
  __syncthreads();

  int n;
  float T;
  for (;;) {
    if (tid == 0) sh_cnt = 0;
    __syncthreads();
    const float thr = sh_thr;
    for (int i = tid * 8; i < F; i += TPB * 8) {
      uint4 pk = *(const uint4*)(row + i);
      unsigned wbits[4] = {pk.x, pk.y, pk.z, pk.w};
#pragma unroll
      for (int u = 0; u < 4; ++u) {
        float v0 = __uint_as_float((wbits[u] & 0xFFFFu) << 16);
        float v1 = __uint_as_float(wbits[u] & 0xFFFF0000u);
        if (v0 > thr) {
          int p = atomicAdd(&sh_cnt, 1);
          if (p < TK_CAP) { cval[p] = v0; cidx[p] = i + 2 * u; }
        }
        if (v1 > thr) {
          int p = atomicAdd(&sh_cnt, 1);
          if (p < TK_CAP) { cval[p] = v1; cidx[p] = i + 2 * u + 1; }
        }
      }
    }
    __syncthreads();
    n = sh_cnt;
    const bool ok = (n >= 64 && n <= TK_CAP);
    if (ok) {
      // radix-select 64th largest among collected (all > 0)
      if (tid == 0) { sh_prefix = 0u; sh_need = 64u; }
      __syncthreads();
      for (int pass = 0; pass < 4; ++pass) {
        const int shift = 24 - 8 * pass;
        hist[tid] = 0u;
        __syncthreads();
        const unsigned prefix = sh_prefix;
        const unsigned maskhi = (pass == 0) ? 0u : (0xFFFFFFFFu << (shift + 8));
        for (int q = tid; q < n; q += TPB) {
          unsigned k = __float_as_uint(cval[q]);
          if ((k & maskhi) == prefix) atomicAdd(&hist[(k >> shift) & 255], 1u);
        }
        __syncthreads();
        if (tid == 0) {
          unsigned need = sh_need, cum = 0;
          int bsel = 0;
          for (int bin = 255; bin >= 0; --bin) {
            if (cum + hist[bin] >= need) { bsel = bin; break; }
            cum += hist[bin];
          }
          sh_prefix = prefix | ((unsigned)bsel << shift);
          sh_need = need - cum;
        }
        __syncthreads();
      }
      T = __uint_as_float(sh_prefix);
      if (thr < T - TK_EPS) break;           // margin certified
      if (tid == 0) sh_thr = T - 2.f * TK_EPS;  // retry (shouldn't happen)
    } else {
      if (tid == 0) sh_thr = (n < 64) ? fmaxf(thr - 0.75f, 1e-3f) : thr + 0.75f;
    }
    __syncthreads();
  }

  // classify collected
  if (tid == 0) { sh_out = 0; sh_band = 0; }
  __syncthreads();
  const float hicut = T + TK_EPS, locut = T - TK_EPS;
  float* ovals = vals + (size_t)b * 64;
  int* oidx = idxs + (size_t)b * 64;
  for (int q = tid; q < n; q += TPB) {
    const float v = cval[q];
    if (v > hicut) {
      int p = atomicAdd(&sh_out, 1);
      ovals[p] = v; oidx[p] = cidx[q];
    } else if (v >= locut) {
      int p = atomicAdd(&sh_band, 1);
      if (p < BAND_CAP) bcand[p] = cidx[q];
    }
  }
  __syncthreads();
  const int s = sh_out;
  const int bn = sh_band < BAND_CAP ? sh_band : BAND_CAP;
  const int needk = 64 - s;
  const int lane = tid & 63, wv = tid >> 6;
  // exact fp64 for band candidates (one wave per candidate)
  for (int q = wv; q < bn; q += 4) {
    const float* wr = W + (size_t)bcand[q] * D;
    double sum = 0.0;
    for (int d = lane; d < D; d += 64) sum += xs[d] * (double)wr[d];
#pragma unroll
    for (int m = 32; m > 0; m >>= 1) sum += __shfl_xor(sum, m, 64);
    if (lane == 0) {
      double v = sum + (double)benc[bcand[q]];
      bexact[q] = v > 0.0 ? v : 0.0;
    }
  }
  __syncthreads();
  if (tid < bn) {
    const double v = bexact[tid];
    const int id = bcand[tid];
    int rank = 0;
    for (int j = 0; j < bn; ++j)
      rank += (bexact[j] > v) || (bexact[j] == v && bcand[j] < id);
    if (rank < needk) { ovals[s + rank] = (float)v; oidx[s + rank] = id; }
  }
  __syncthreads();
  if (need_exact) {  // recompute all 64 selected vals exactly (up path)
    for (int k = wv; k < 64; k += 4) {
      const int id = oidx[k];
      const float* wr = W + (size_t)id * D;
      double sum = 0.0;
      for (int d = lane; d < D; d += 64) sum += xs[d] * (double)wr[d];
#pragma unroll
      for (int m = 32; m > 0; m >>= 1) sum += __shfl_xor(sum, m, 64);
      if (lane == 0) {
        double v = sum + (double)benc[id];
        ovals[k] = (float)(v > 0.0 ? v : 0.0);
      }
    }
  }
}

// ---------------------------------------------------------------------------
// Transpose W_dec (D,F) -> (F,D)
// ---------------------------------------------------------------------------
__global__ __launch_bounds__(TPB) void transpose_df(
    const float* __restrict__ in, float* __restrict__ out, int D, int F) {
  __shared__ float tile[32][33];
  const int f0 = blockIdx.x * 32;
  const int d0 = blockIdx.y * 32;
  const int tx = threadIdx.x & 31;
  const int ty = threadIdx.x >> 5;
#pragma unroll
  for (int i = 0; i < 4; ++i)
    tile[ty + i * 8][tx] = in[(size_t)(d0 + ty + i * 8) * F + f0 + tx];
  __syncthreads();
#pragma unroll
  for (int i = 0; i < 4; ++i)
    out[(size_t)(f0 + ty + i * 8) * D + d0 + tx] = tile[tx][ty + i * 8];
}

// ---------------------------------------------------------------------------
// Sparse decode (float4): out[b,:] = bdec + sum_k vals[b,k] * WT[idx[b,k],:]
// ---------------------------------------------------------------------------
__global__ __launch_bounds__(TPB) void decode64(
    const float* __restrict__ WT, const float* __restrict__ bdec,
    const float* __restrict__ vals, const int* __restrict__ idxs,
    float* __restrict__ out, int D) {
  const int b = blockIdx.x;
  __shared__ float sv[64];
  __shared__ int si[64];
  const int tid = threadIdx.x;
  if (tid < 64) {
    sv[tid] = vals[(size_t)b * 64 + tid];
    si[tid] = idxs[(size_t)b * 64 + tid];
  }
  __syncthreads();
  const int nd4 = D >> 2;
  for (int d4 = tid; d4 < nd4; d4 += TPB) {
    f32x4 acc = *(const f32x4*)(bdec + d4 * 4);
#pragma unroll 8
    for (int k = 0; k < 64; ++k)
      acc += *(const f32x4*)(WT + (size_t)si[k] * D + d4 * 4) * sv[k];
    *(f32x4*)(out + (size_t)b * D + d4 * 4) = acc;
  }
}

// ---------------------------------------------------------------------------
// approx_acts: connection matching + wave-parallel cooperative dots
// ---------------------------------------------------------------------------
__global__ __launch_bounds__(TPB) void contrib(
    const int* __restrict__ conn, const float* __restrict__ Wencd,
    const float* __restrict__ WTdecu,
    const float* __restrict__ up_vals, const int* __restrict__ up_idx,
    const int* __restrict__ down_idx,
    float* __restrict__ approx, int D, int C) {
  const int b = blockIdx.x;
  __shared__ int sui[64];
  __shared__ float suv[64];
  __shared__ int sdi[64];
  __shared__ float sacc[64];
  __shared__ int queue[2048];
  __shared__ int qn;
  const int tid = threadIdx.x;
  if (tid < 64) {
    sui[tid] = up_idx[(size_t)b * 64 + tid];
    suv[tid] = up_vals[(size_t)b * 64 + tid];
    sdi[tid] = down_idx[(size_t)b * 64 + tid];
    sacc[tid] = 0.0f;
  }
  if (tid == 0) qn = 0;
  __syncthreads();
  const int npairs = 64 * C;
  for (int p = tid; p < npairs; p += TPB) {
    int kd = p / C, c = p - kd * C;
    int f = conn[(size_t)sdi[kd] * C + c];
    if (f < 0) continue;
    for (int ku = 0; ku < 64; ++ku) {
      if (sui[ku] == f) {  // up_idx distinct -> at most one match
        int q = atomicAdd(&qn, 1);
        queue[q] = (kd << 8) | ku;
        break;
      }
    }
  }
  __syncthreads();
  const int n = qn;
  const int lane = tid & 63, wv = tid >> 6;
  for (int q = wv; q < n; q += 4) {
    const int kd = queue[q] >> 8, ku = queue[q] & 255;
    const float* wd = Wencd + (size_t)sdi[kd] * D;
    const float* wu = WTdecu + (size_t)sui[ku] * D;
    float s = 0.0f;
    for (int d = lane; d < D; d += 64) s += wd[d] * wu[d];
#pragma unroll
    for (int m = 32; m > 0; m >>= 1) s += __shfl_xor(s, m, 64);
    if (lane == 0) atomicAdd(&sacc[kd], suv[ku] * s);
  }
  __syncthreads();
  if (tid < 64) approx[(size_t)b * 64 + tid] = sacc[tid];
}

// ---------------------------------------------------------------------------
extern "C" void kernel_launch(void* const* d_in, const int* in_sizes, int n_in,
                              void* d_out, int out_size, void* d_ws, size_t ws_size,
                              hipStream_t stream) {
  const float* x_up   = (const float*)d_in[0];
  const float* x_down = (const float*)d_in[1];
  const float* Wenc_u = (const float*)d_in[2];
  const float* benc_u = (const float*)d_in[3];
  const float* Wdec_u = (const float*)d_in[4];
  const float* bdec_u = (const float*)d_in[5];
  const float* Wenc_d = (const float*)d_in[6];
  const float* benc_d = (const float*)d_in[7];
  const float* Wdec_d = (const float*)d_in[8];
  const float* bdec_d = (const float*)d_in[9];
  const int*   conn   = (const int*)d_in[10];

  const int D = in_sizes[5];           // 768
  const int B = in_sizes[0] / D;       // 1024
  const int F = in_sizes[3];           // 24576
  const int C = in_sizes[10] / F;      // 32
  const int nkt = D / 32;              // 24

  float* out = (float*)d_out;
  char* w = (char*)d_ws;

  // ws layout (bytes):
  //  [0, B*F*2)                    pre bf16       (48 MB)  } overlapped later
  //  [B*F*2, +F*D*2)               Wperm bf16     (36 MB)  } by WT fp32 (72MB)
  //  then xupPerm, xdnPerm (B*D*2 each), then vals/idx/approx
  __bf16* pre16 = (__bf16*)w;
  bf16x8* Wperm = (bf16x8*)(w + (size_t)B * F * 2);
  bf16x8* xuP   = (bf16x8*)(w + (size_t)B * F * 2 + (size_t)F * D * 2);
  bf16x8* xdP   = xuP + (size_t)B * D / 8;
  float* up_vals = (float*)(xdP + (size_t)B * D / 8);
  int*   up_idx  = (int*)(up_vals + (size_t)B * 64);
  float* dn_vals = (float*)(up_idx + (size_t)B * 64);
  int*   dn_idx  = (int*)(dn_vals + (size_t)B * 64);
  float* approx  = (float*)(dn_idx + (size_t)B * 64);
  float* WT = (float*)w;  // reuses pre+Wperm region after both are dead

  dim3 packW_grid(F / 128, nkt);
  dim3 packX_grid(B / 128, nkt);
  dim3 gemm_grid(F / 128, B / 128);
  dim3 tr_grid(F / 32, D / 32);

  // ---- upstream encode ----
  pack_tiles<<<packX_grid, TPB, 0, stream>>>(x_up, bdec_u, xuP, D);
  pack_tiles<<<packW_grid, TPB, 0, stream>>>(Wenc_u, nullptr, Wperm, D);
  enc_gemm_bf<<<gemm_grid, TPB, 0, stream>>>(xuP, Wperm, benc_u, pre16, nkt, F);
  topk_sel<<<B, TPB, 0, stream>>>((const unsigned short*)pre16, x_up, Wenc_u,
                                  benc_u, bdec_u, up_vals, up_idx, D, F, 1);
  // ---- downstream encode (dn_vals unused by output -> need_exact=0) ----
  pack_tiles<<<packX_grid, TPB, 0, stream>>>(x_down, bdec_d, xdP, D);
  pack_tiles<<<packW_grid, TPB, 0, stream>>>(Wenc_d, nullptr, Wperm, D);
  enc_gemm_bf<<<gemm_grid, TPB, 0, stream>>>(xdP, Wperm, benc_d, pre16, nkt, F);
  topk_sel<<<B, TPB, 0, stream>>>((const unsigned short*)pre16, x_down, Wenc_d,
                                  benc_d, bdec_d, dn_vals, dn_idx, D, F, 0);

  // ---- decode + contributions ----
  transpose_df<<<tr_grid, TPB, 0, stream>>>(Wdec_u, WT, D, F);
  decode64<<<B, TPB, 0, stream>>>(WT, bdec_u, up_vals, up_idx, out, D);
  contrib<<<B, TPB, 0, stream>>>(conn, Wenc_d, WT, up_vals, up_idx, dn_idx,
                                 approx, D, C);
  transpose_df<<<tr_grid, TPB, 0, stream>>>(Wdec_d, WT, D, F);
  decode64<<<B, TPB, 0, stream>>>(WT, bdec_d, approx, dn_idx, out + (size_t)B * D, D);
}

// Round 4
// 694.198 us; speedup vs baseline: 3.9624x; 1.2166x over previous
//
#include <hip/hip_runtime.h>
#include <hip/hip_bf16.h>

#define TPB 256

typedef __attribute__((ext_vector_type(4))) float f32x4;
typedef __bf16 bf16x8 __attribute__((ext_vector_type(8)));

// async global->LDS, 16B per lane. LDS dest must be wave-uniform base;
// HW writes lane i's 16B at base + i*16 (m97-verified pattern).
__device__ __forceinline__ void gload16(const bf16x8* g, bf16x8* l) {
  __builtin_amdgcn_global_load_lds(
      (const __attribute__((address_space(1))) unsigned int*)g,
      (__attribute__((address_space(3))) unsigned int*)l, 16, 0, 0);
}

// wave-cooperative fp64 dot of LDS xs[] with global fp32 row wr[].
// D==768 path: 12 loads issued back-to-back (one vmcnt drain per dot,
// not twelve) -- the round-3 topk was latency-serialized here.
__device__ __forceinline__ double dot_w64(const double* xs, const float* wr,
                                          int lane, int D) {
  double sum = 0.0;
  if ((D >> 6) == 12) {
    float wv[12];
#pragma unroll
    for (int u = 0; u < 12; ++u) wv[u] = wr[lane + (u << 6)];
#pragma unroll
    for (int u = 0; u < 12; ++u) sum += xs[lane + (u << 6)] * (double)wv[u];
  } else {
    for (int d = lane; d < D; d += 64) sum += xs[d] * (double)wr[d];
  }
#pragma unroll
  for (int m = 32; m > 0; m >>= 1) sum += __shfl_xor(sum, m, 64);
  return sum;
}

// wave-cooperative fp32 dot of two global rows (same ILP trick).
__device__ __forceinline__ float dotf_w64(const float* a, const float* b,
                                          int lane, int D) {
  float s = 0.f;
  if ((D >> 6) == 12) {
    float av[12], bv[12];
#pragma unroll
    for (int u = 0; u < 12; ++u) {
      av[u] = a[lane + (u << 6)];
      bv[u] = b[lane + (u << 6)];
    }
#pragma unroll
    for (int u = 0; u < 12; ++u) s += av[u] * bv[u];
  } else {
    for (int d = lane; d < D; d += 64) s += a[d] * b[d];
  }
#pragma unroll
  for (int m = 32; m > 0; m >>= 1) s += __shfl_xor(s, m, 64);
  return s;
}

// ---------------------------------------------------------------------------
// pack_tiles: fp32 [R,D] (optionally minus `sub`) -> bf16 tile-permuted
// layout [R/128][D/32][512] of bf16x8: entry q = g*128 + row holds
// src[r0+row][k0+g*8 .. +8] == the LDS image enc_gemm_bf stages.
// ---------------------------------------------------------------------------
__global__ __launch_bounds__(TPB) void pack_tiles(
    const float* __restrict__ src, const float* __restrict__ sub,
    bf16x8* __restrict__ dst, int D) {
  const int r0 = blockIdx.x * 128;
  const int k0 = blockIdx.y * 32;
  const size_t tile = ((size_t)blockIdx.x * gridDim.y + blockIdx.y) * 512;
#pragma unroll
  for (int e = 0; e < 2; ++e) {
    const int q = e * 256 + threadIdx.x;
    const int row = q & 127, g = q >> 7;
    const float* s = src + (size_t)(r0 + row) * D + k0 + g * 8;
    f32x4 v0 = *(const f32x4*)s;
    f32x4 v1 = *(const f32x4*)(s + 4);
    if (sub) {
      const float* bp = sub + k0 + g * 8;
      v0 = v0 - *(const f32x4*)bp;
      v1 = v1 - *(const f32x4*)(bp + 4);
    }
    bf16x8 o;
#pragma unroll
    for (int u = 0; u < 4; ++u) o[u] = (__bf16)v0[u];
#pragma unroll
    for (int u = 0; u < 4; ++u) o[u + 4] = (__bf16)v1[u];
    dst[tile + q] = o;
  }
}

// ---------------------------------------------------------------------------
// pre = relu(A @ W^T + benc), pure bf16 MFMA, m97 structure.
// 128x128 tile, BK=32, 4 waves (2x2 of 64x64), pre stored bf16.
// ---------------------------------------------------------------------------
__global__ __launch_bounds__(TPB) void enc_gemm_bf(
    const bf16x8* __restrict__ A,   // packed [B/128][nkt][512]
    const bf16x8* __restrict__ W,   // packed [F/128][nkt][512]
    const float* __restrict__ benc,
    __bf16* __restrict__ pre,       // [B,F] bf16
    int nkt, int F) {
  __shared__ bf16x8 As[512], Ws[512];
  const int t = threadIdx.x;
  const int lane = t & 63, wv = t >> 6;
  const int wm = (wv >> 1) * 64, wn = (wv & 1) * 64;
  const int lrow = lane & 15, quad = lane >> 4;
  const size_t Ab = (size_t)blockIdx.y * nkt * 512;
  const size_t Wb = (size_t)blockIdx.x * nkt * 512;

  f32x4 acc[4][4];
#pragma unroll
  for (int i = 0; i < 4; ++i)
#pragma unroll
    for (int j = 0; j < 4; ++j) acc[i][j] = (f32x4){0.f, 0.f, 0.f, 0.f};

  for (int kt = 0; kt < nkt; ++kt) {
    __syncthreads();
    const bf16x8* ag = A + Ab + (size_t)kt * 512 + wv * 128;
    const bf16x8* wg = W + Wb + (size_t)kt * 512 + wv * 128;
    bf16x8* al = As + wv * 128;
    bf16x8* wl = Ws + wv * 128;
    gload16(ag + lane, al);
    gload16(ag + 64 + lane, al + 64);
    gload16(wg + lane, wl);
    gload16(wg + 64 + lane, wl + 64);
    __syncthreads();
    bf16x8 af[4];
#pragma unroll
    for (int i = 0; i < 4; ++i) af[i] = As[quad * 128 + wm + i * 16 + lrow];
#pragma unroll
    for (int j = 0; j < 4; ++j) {
      bf16x8 bfr = Ws[quad * 128 + wn + j * 16 + lrow];
#pragma unroll
      for (int i = 0; i < 4; ++i)
        acc[i][j] = __builtin_amdgcn_mfma_f32_16x16x32_bf16(af[i], bfr, acc[i][j], 0, 0, 0);
    }
  }
  const int bf0 = blockIdx.x * 128, bb = blockIdx.y * 128;
#pragma unroll
  for (int j = 0; j < 4; ++j) {
    const int col = bf0 + wn + j * 16 + lrow;
    const float bc = benc[col];
#pragma unroll
    for (int i = 0; i < 4; ++i) {
      const int row0 = bb + wm + i * 16 + quad * 4;
#pragma unroll
      for (int rg = 0; rg < 4; ++rg) {
        float v = acc[i][j][rg] + bc;
        v = v > 0.f ? v : 0.f;
        pre[(size_t)(row0 + rg) * F + col] = (__bf16)v;
      }
    }
  }
}

// ---------------------------------------------------------------------------
// topk_sel: top-64 selection matching exact-fp64 ranking.
//  1. collect (val,idx) > thr into LDS (1 global pass typical)
//  2. in-LDS radix-select T = 64th-largest approx
//  3. > T+eps: sure-in, emit approx; [T-eps,T+eps]: exact fp64 rerank
// Values emitted approx except band entries (error budget analysis: output
// perturbation < 0.01 << 0.083 threshold; selection provably exact given
// |approx-exact| <= 0.024 <= eps/2).
// ---------------------------------------------------------------------------
#define TK_CAP 2048
#define BAND_CAP 256
#define TK_EPS 0.06f

__global__ __launch_bounds__(TPB) void topk_sel(
    const unsigned short* __restrict__ pre,  // [B,F] bf16 bits
    const float* __restrict__ x, const float* __restrict__ W,
    const float* __restrict__ benc, const float* __restrict__ bdec,
    float* __restrict__ vals, int* __restrict__ idxs,
    int D, int F) {
  const int b = blockIdx.x;
  const int tid = threadIdx.x;
  const unsigned short* row = pre + (size_t)b * F;

  __shared__ float cval[TK_CAP];
  __shared__ int cidx[TK_CAP];
  __shared__ unsigned hist[256];
  __shared__ double xs[768];
  __shared__ int bcand[BAND_CAP];
  __shared__ double bexact[BAND_CAP];
  __shared__ int sh_cnt, sh_out, sh_band;
  __shared__ float sh_thr;
  __shared__ unsigned sh_prefix, sh_need;

  for (int d = tid; d < D; d += TPB)
    xs[d] = (double)x[(size_t)b * D + d] - (double)bdec[d];
  if (tid == 0) sh_thr = 1.75f;
  __syncthreads();

  int n;
  float T;
  for (;;) {
    if (tid == 0) sh_cnt = 0;
    __syncthreads();
    const float thr = sh_thr;
    for (int i = tid * 8; i < F; i += TPB * 8) {
      uint4 pk = *(const uint4*)(row + i);
      unsigned wbits[4] = {pk.x, pk.y, pk.z, pk.w};
#pragma unroll
      for (int u = 0; u < 4; ++u) {
        float v0 = __uint_as_float((wbits[u] & 0xFFFFu) << 16);
        float v1 = __uint_as_float(wbits[u] & 0xFFFF0000u);
        if (v0 > thr) {
          int p = atomicAdd(&sh_cnt, 1);
          if (p < TK_CAP) { cval[p] = v0; cidx[p] = i + 2 * u; }
        }
        if (v1 > thr) {
          int p = atomicAdd(&sh_cnt, 1);
          if (p < TK_CAP) { cval[p] = v1; cidx[p] = i + 2 * u + 1; }
        }
      }
    }
    __syncthreads();
    n = sh_cnt;
    if (n >= 64 && n <= TK_CAP) {
      // radix-select 64th largest among collected (all > 0)
      if (tid == 0) { sh_prefix = 0u; sh_need = 64u; }
      __syncthreads();
      for (int pass = 0; pass < 4; ++pass) {
        const int shift = 24 - 8 * pass;
        hist[tid] = 0u;
        __syncthreads();
        const unsigned prefix = sh_prefix;
        const unsigned maskhi = (pass == 0) ? 0u : (0xFFFFFFFFu << (shift + 8));
        for (int q = tid; q < n; q += TPB) {
          unsigned k = __float_as_uint(cval[q]);
          if ((k & maskhi) == prefix) atomicAdd(&hist[(k >> shift) & 255], 1u);
        }
        __syncthreads();
        if (tid == 0) {
          unsigned need = sh_need, cum = 0;
          int bsel = 0;
          for (int bin = 255; bin >= 0; --bin) {
            if (cum + hist[bin] >= need) { bsel = bin; break; }
            cum += hist[bin];
          }
          sh_prefix = prefix | ((unsigned)bsel << shift);
          sh_need = need - cum;
        }
        __syncthreads();
      }
      T = __uint_as_float(sh_prefix);
      if (thr < T - TK_EPS) break;              // margin certified
      if (tid == 0) sh_thr = T - 2.f * TK_EPS;  // retry (shouldn't happen)
    } else {
      if (tid == 0) sh_thr = (n < 64) ? fmaxf(thr - 0.75f, 1e-3f) : thr + 0.75f;
    }
    __syncthreads();
  }

  // classify collected
  if (tid == 0) { sh_out = 0; sh_band = 0; }
  __syncthreads();
  const float hicut = T + TK_EPS, locut = T - TK_EPS;
  float* ovals = vals + (size_t)b * 64;
  int* oidx = idxs + (size_t)b * 64;
  for (int q = tid; q < n; q += TPB) {
    const float v = cval[q];
    if (v > hicut) {
      int p = atomicAdd(&sh_out, 1);
      ovals[p] = v; oidx[p] = cidx[q];
    } else if (v >= locut) {
      int p = atomicAdd(&sh_band, 1);
      if (p < BAND_CAP) bcand[p] = cidx[q];
    }
  }
  __syncthreads();
  const int s = sh_out;
  const int bn = sh_band < BAND_CAP ? sh_band : BAND_CAP;
  const int needk = 64 - s;
  const int lane = tid & 63, wv = tid >> 6;
  for (int q = wv; q < bn; q += 4) {
    double sum = dot_w64(xs, W + (size_t)bcand[q] * D, lane, D);
    if (lane == 0) {
      double v = sum + (double)benc[bcand[q]];
      bexact[q] = v > 0.0 ? v : 0.0;
    }
  }
  __syncthreads();
  if (tid < bn) {
    const double v = bexact[tid];
    const int id = bcand[tid];
    int rank = 0;
    for (int j = 0; j < bn; ++j)
      rank += (bexact[j] > v) || (bexact[j] == v && bcand[j] < id);
    if (rank < needk) { ovals[s + rank] = (float)v; oidx[s + rank] = id; }
  }
}

// ---------------------------------------------------------------------------
// Transpose W_dec (D,F) -> (F,D)
// ---------------------------------------------------------------------------
__global__ __launch_bounds__(TPB) void transpose_df(
    const float* __restrict__ in, float* __restrict__ out, int D, int F) {
  __shared__ float tile[32][33];
  const int f0 = blockIdx.x * 32;
  const int d0 = blockIdx.y * 32;
  const int tx = threadIdx.x & 31;
  const int ty = threadIdx.x >> 5;
#pragma unroll
  for (int i = 0; i < 4; ++i)
    tile[ty + i * 8][tx] = in[(size_t)(d0 + ty + i * 8) * F + f0 + tx];
  __syncthreads();
#pragma unroll
  for (int i = 0; i < 4; ++i)
    out[(size_t)(f0 + ty + i * 8) * D + d0 + tx] = tile[tx][ty + i * 8];
}

// ---------------------------------------------------------------------------
// Sparse decode (float4): out[b,:] = bdec + sum_k vals[b,k] * WT[idx[b,k],:]
// ---------------------------------------------------------------------------
__global__ __launch_bounds__(TPB) void decode64(
    const float* __restrict__ WT, const float* __restrict__ bdec,
    const float* __restrict__ vals, const int* __restrict__ idxs,
    float* __restrict__ out, int D) {
  const int b = blockIdx.x;
  __shared__ float sv[64];
  __shared__ int si[64];
  const int tid = threadIdx.x;
  if (tid < 64) {
    sv[tid] = vals[(size_t)b * 64 + tid];
    si[tid] = idxs[(size_t)b * 64 + tid];
  }
  __syncthreads();
  const int nd4 = D >> 2;
  for (int d4 = tid; d4 < nd4; d4 += TPB) {
    f32x4 acc = *(const f32x4*)(bdec + d4 * 4);
#pragma unroll 8
    for (int k = 0; k < 64; ++k)
      acc += *(const f32x4*)(WT + (size_t)si[k] * D + d4 * 4) * sv[k];
    *(f32x4*)(out + (size_t)b * D + d4 * 4) = acc;
  }
}

// ---------------------------------------------------------------------------
// approx_acts: connection matching + wave-parallel cooperative dots
// ---------------------------------------------------------------------------
__global__ __launch_bounds__(TPB) void contrib(
    const int* __restrict__ conn, const float* __restrict__ Wencd,
    const float* __restrict__ WTdecu,
    const float* __restrict__ up_vals, const int* __restrict__ up_idx,
    const int* __restrict__ down_idx,
    float* __restrict__ approx, int D, int C) {
  const int b = blockIdx.x;
  __shared__ int sui[64];
  __shared__ float suv[64];
  __shared__ int sdi[64];
  __shared__ float sacc[64];
  __shared__ int queue[2048];
  __shared__ int qn;
  const int tid = threadIdx.x;
  if (tid < 64) {
    sui[tid] = up_idx[(size_t)b * 64 + tid];
    suv[tid] = up_vals[(size_t)b * 64 + tid];
    sdi[tid] = down_idx[(size_t)b * 64 + tid];
    sacc[tid] = 0.0f;
  }
  if (tid == 0) qn = 0;
  __syncthreads();
  const int npairs = 64 * C;
  for (int p = tid; p < npairs; p += TPB) {
    int kd = p / C, c = p - kd * C;
    int f = conn[(size_t)sdi[kd] * C + c];
    if (f < 0) continue;
    for (int ku = 0; ku < 64; ++ku) {
      if (sui[ku] == f) {  // up_idx distinct -> at most one match
        int q = atomicAdd(&qn, 1);
        queue[q] = (kd << 8) | ku;
        break;
      }
    }
  }
  __syncthreads();
  const int n = qn;
  const int lane = tid & 63, wv = tid >> 6;
  for (int q = wv; q < n; q += 4) {
    const int kd = queue[q] >> 8, ku = queue[q] & 255;
    float s = dotf_w64(Wencd + (size_t)sdi[kd] * D,
                       WTdecu + (size_t)sui[ku] * D, lane, D);
    if (lane == 0) atomicAdd(&sacc[kd], suv[ku] * s);
  }
  __syncthreads();
  if (tid < 64) approx[(size_t)b * 64 + tid] = sacc[tid];
}

// ---------------------------------------------------------------------------
extern "C" void kernel_launch(void* const* d_in, const int* in_sizes, int n_in,
                              void* d_out, int out_size, void* d_ws, size_t ws_size,
                              hipStream_t stream) {
  const float* x_up   = (const float*)d_in[0];
  const float* x_down = (const float*)d_in[1];
  const float* Wenc_u = (const float*)d_in[2];
  const float* benc_u = (const float*)d_in[3];
  const float* Wdec_u = (const float*)d_in[4];
  const float* bdec_u = (const float*)d_in[5];
  const float* Wenc_d = (const float*)d_in[6];
  const float* benc_d = (const float*)d_in[7];
  const float* Wdec_d = (const float*)d_in[8];
  const float* bdec_d = (const float*)d_in[9];
  const int*   conn   = (const int*)d_in[10];

  const int D = in_sizes[5];           // 768
  const int B = in_sizes[0] / D;       // 1024
  const int F = in_sizes[3];           // 24576
  const int C = in_sizes[10] / F;      // 32
  const int nkt = D / 32;              // 24

  float* out = (float*)d_out;
  char* w = (char*)d_ws;

  __bf16* pre16 = (__bf16*)w;
  bf16x8* Wperm = (bf16x8*)(w + (size_t)B * F * 2);
  bf16x8* xuP   = (bf16x8*)(w + (size_t)B * F * 2 + (size_t)F * D * 2);
  bf16x8* xdP   = xuP + (size_t)B * D / 8;
  float* up_vals = (float*)(xdP + (size_t)B * D / 8);
  int*   up_idx  = (int*)(up_vals + (size_t)B * 64);
  float* dn_vals = (float*)(up_idx + (size_t)B * 64);
  int*   dn_idx  = (int*)(dn_vals + (size_t)B * 64);
  float* approx  = (float*)(dn_idx + (size_t)B * 64);
  float* WT = (float*)w;  // reuses pre+Wperm region after both are dead

  dim3 packW_grid(F / 128, nkt);
  dim3 packX_grid(B / 128, nkt);
  dim3 gemm_grid(F / 128, B / 128);
  dim3 tr_grid(F / 32, D / 32);

  // ---- upstream encode ----
  pack_tiles<<<packX_grid, TPB, 0, stream>>>(x_up, bdec_u, xuP, D);
  pack_tiles<<<packW_grid, TPB, 0, stream>>>(Wenc_u, nullptr, Wperm, D);
  enc_gemm_bf<<<gemm_grid, TPB, 0, stream>>>(xuP, Wperm, benc_u, pre16, nkt, F);
  topk_sel<<<B, TPB, 0, stream>>>((const unsigned short*)pre16, x_up, Wenc_u,
                                  benc_u, bdec_u, up_vals, up_idx, D, F);
  // ---- downstream encode ----
  pack_tiles<<<packX_grid, TPB, 0, stream>>>(x_down, bdec_d, xdP, D);
  pack_tiles<<<packW_grid, TPB, 0, stream>>>(Wenc_d, nullptr, Wperm, D);
  enc_gemm_bf<<<gemm_grid, TPB, 0, stream>>>(xdP, Wperm, benc_d, pre16, nkt, F);
  topk_sel<<<B, TPB, 0, stream>>>((const unsigned short*)pre16, x_down, Wenc_d,
                                  benc_d, bdec_d, dn_vals, dn_idx, D, F);

  // ---- decode + contributions ----
  transpose_df<<<tr_grid, TPB, 0, stream>>>(Wdec_u, WT, D, F);
  decode64<<<B, TPB, 0, stream>>>(WT, bdec_u, up_vals, up_idx, out, D);
  contrib<<<B, TPB, 0, stream>>>(conn, Wenc_d, WT, up_vals, up_idx, dn_idx,
                                 approx, D, C);
  transpose_df<<<tr_grid, TPB, 0, stream>>>(Wdec_d, WT, D, F);
  decode64<<<B, TPB, 0, stream>>>(WT, bdec_d, approx, dn_idx, out + (size_t)B * D, D);
}